// Round 1
// baseline (1288.207 us; speedup 1.0000x reference)
//
#include <hip/hip_runtime.h>

#define NL 16
#define HID 16
#define LAT 64
#define BATCHN 262144

__device__ __forceinline__ float leaky(float v) { return v > 0.f ? v : 0.01f * v; }

// One coupling layer. PR = parity of the masked-in (read) half.
// zr = 32 read-half elements (unchanged by this layer), zw = 32 write-half elements.
template<int PR>
__device__ __forceinline__ void layer_step(
    const float* __restrict__ W1s, const float* __restrict__ b1s,
    const float* __restrict__ W2s, const float* __restrict__ b2s,
    const float* __restrict__ W1t, const float* __restrict__ b1t,
    const float* __restrict__ W2t, const float* __restrict__ b2t,
    const float* __restrict__ zr, float* __restrict__ zw, float& ld)
{
  float hs[HID], ht[HID];
#pragma unroll
  for (int h = 0; h < HID; ++h) {
    float as = b1s[h];
    float at = b1t[h];
#pragma unroll
    for (int j = 0; j < 32; ++j) {
      const float zv = zr[j];
      as = fmaf(W1s[h * LAT + 2 * j + PR], zv, as);
      at = fmaf(W1t[h * LAT + 2 * j + PR], zv, at);
    }
    hs[h] = leaky(as);
    ht[h] = leaky(at);
  }
  constexpr int PW = 1 - PR;
#pragma unroll
  for (int j = 0; j < 32; ++j) {
    const int d = 2 * j + PW;
    float ss = b2s[d];
    float tt = b2t[d];
#pragma unroll
    for (int h = 0; h < HID; ++h) {
      ss = fmaf(W2s[d * HID + h], hs[h], ss);
      tt = fmaf(W2t[d * HID + h], ht[h], tt);
    }
    // tanh(ss) = (e^{2ss}-1)/(e^{2ss}+1); clamp to avoid inf/inf (tanh saturated anyway)
    ss = fminf(fmaxf(ss, -10.f), 10.f);
    const float e2 = __expf(2.f * ss);
    const float sc = __fdividef(e2 - 1.f, e2 + 1.f);
    zw[j] = zw[j] * __expf(sc) + tt;
    ld += sc;
  }
}

__global__ __launch_bounds__(256) void realnvp_fwd(
    const float* __restrict__ x,
    const float* __restrict__ sW1, const float* __restrict__ sb1,
    const float* __restrict__ sW2, const float* __restrict__ sb2,
    const float* __restrict__ tW1, const float* __restrict__ tb1,
    const float* __restrict__ tW2, const float* __restrict__ tb2,
    float* __restrict__ out)
{
  const int row = blockIdx.x * blockDim.x + threadIdx.x;
  const float4* __restrict__ xr = reinterpret_cast<const float4*>(x + (long)row * LAT);
  float ze[32], zo[32];   // parity-packed row: ze[j] = z[2j], zo[j] = z[2j+1]
#pragma unroll
  for (int q = 0; q < 16; ++q) {
    const float4 v = xr[q];
    ze[2 * q]     = v.x;  zo[2 * q]     = v.y;
    ze[2 * q + 1] = v.z;  zo[2 * q + 1] = v.w;
  }
  float ld = 0.f;
  // Layer pair: even layer reads even parity (PR=0) writes odd; odd layer reads odd writes even.
#pragma unroll 1
  for (int lp = 0; lp < NL / 2; ++lp) {
    const int l0 = 2 * lp, l1 = 2 * lp + 1;
    layer_step<0>(sW1 + l0 * HID * LAT, sb1 + l0 * HID,
                  sW2 + l0 * LAT * HID, sb2 + l0 * LAT,
                  tW1 + l0 * HID * LAT, tb1 + l0 * HID,
                  tW2 + l0 * LAT * HID, tb2 + l0 * LAT,
                  ze, zo, ld);
    layer_step<1>(sW1 + l1 * HID * LAT, sb1 + l1 * HID,
                  sW2 + l1 * LAT * HID, sb2 + l1 * LAT,
                  tW1 + l1 * HID * LAT, tb1 + l1 * HID,
                  tW2 + l1 * LAT * HID, tb2 + l1 * LAT,
                  zo, ze, ld);
  }
  float4* __restrict__ outz = reinterpret_cast<float4*>(out + (long)row * LAT);
#pragma unroll
  for (int q = 0; q < 16; ++q) {
    float4 v;
    v.x = ze[2 * q];     v.y = zo[2 * q];
    v.z = ze[2 * q + 1]; v.w = zo[2 * q + 1];
    outz[q] = v;
  }
  out[(long)BATCHN * LAT + row] = ld;  // log-det tail
}

extern "C" void kernel_launch(void* const* d_in, const int* in_sizes, int n_in,
                              void* d_out, int out_size, void* d_ws, size_t ws_size,
                              hipStream_t stream) {
  const float* x   = (const float*)d_in[0];
  const float* sW1 = (const float*)d_in[1];
  const float* sb1 = (const float*)d_in[2];
  const float* sW2 = (const float*)d_in[3];
  const float* sb2 = (const float*)d_in[4];
  const float* tW1 = (const float*)d_in[5];
  const float* tb1 = (const float*)d_in[6];
  const float* tW2 = (const float*)d_in[7];
  const float* tb2 = (const float*)d_in[8];
  float* out = (float*)d_out;
  dim3 grid(BATCHN / 256), block(256);
  hipLaunchKernelGGL(realnvp_fwd, grid, block, 0, stream,
                     x, sW1, sb1, sW2, sb2, tW1, tb1, tW2, tb2, out);
}

// Round 3
// 231.831 us; speedup vs baseline: 5.5567x; 5.5567x over previous
//
#include <hip/hip_runtime.h>
#include <hip/hip_bf16.h>

#define NL 16
#define HID 16
#define LAT 64
#define BATCHN 262144

typedef __attribute__((ext_vector_type(4))) float f32x4;
typedef __attribute__((ext_vector_type(8))) short b16x8;

// gfx950-verified MFMA (guide §3 / m89): A,B = 8 bf16 (ext_vector(8) short),
// lane 16g+c holds A[row=c][k=8g+j], B[k=8g+j][col=c]; D reg j = D[row=4g+j][col=c].
__device__ __forceinline__ f32x4 MFMA32(b16x8 a, b16x8 b, f32x4 c) {
  return __builtin_amdgcn_mfma_f32_16x16x32_bf16(a, b, c, 0, 0, 0);
}

__device__ __forceinline__ short bfs(float f) {
  __hip_bfloat16 h = __float2bfloat16(f);
  union { __hip_bfloat16 h; short s; } u; u.h = h;
  return u.s;
}
__device__ __forceinline__ float leaky(float v) { return fmaxf(v, 0.01f * v); }

// z-state per lane (lane = 16g+c), batch row = rowbase+16T+c:
//   zst[T][p][uh][j] holds z[row][dim = 16g + 2*(4*uh+j) + p]   (u = 4uh+j = 0..7)
// => zst[T][p] (8 slots) IS the B-operand (k=8g+u) for the K=32 GEMM1 MFMA.
// GEMM2 D tile `to`, reg j lands at slot u=4to+j (dim index m=8g+4to+j, dim=2m+PW).
template<int PR>
__device__ __forceinline__ void layer_step(
    const float* __restrict__ sW1l, const float* __restrict__ sb1l,
    const float* __restrict__ sW2l, const float* __restrict__ sb2l,
    const float* __restrict__ tW1l, const float* __restrict__ tb1l,
    const float* __restrict__ tW2l, const float* __restrict__ tb2l,
    f32x4 (&zst)[2][2][2], float (&ldp)[2], int c, int g)
{
  constexpr int PW = 1 - PR;
  // ---- GEMM1 A: lane holds W1[c][16g+2u+PR], u=0..7 (4 float4s of row c) ----
  const f32x4* w1s4 = (const f32x4*)sW1l;
  const f32x4* w1t4 = (const f32x4*)tW1l;
  b16x8 a1s, a1t;
  {
    const int base = c * 16 + g * 4;
    f32x4 q0 = w1s4[base], q1 = w1s4[base + 1], q2 = w1s4[base + 2], q3 = w1s4[base + 3];
    a1s[0] = bfs(q0[PR]); a1s[1] = bfs(q0[2 + PR]);
    a1s[2] = bfs(q1[PR]); a1s[3] = bfs(q1[2 + PR]);
    a1s[4] = bfs(q2[PR]); a1s[5] = bfs(q2[2 + PR]);
    a1s[6] = bfs(q3[PR]); a1s[7] = bfs(q3[2 + PR]);
    q0 = w1t4[base]; q1 = w1t4[base + 1]; q2 = w1t4[base + 2]; q3 = w1t4[base + 3];
    a1t[0] = bfs(q0[PR]); a1t[1] = bfs(q0[2 + PR]);
    a1t[2] = bfs(q1[PR]); a1t[3] = bfs(q1[2 + PR]);
    a1t[4] = bfs(q2[PR]); a1t[5] = bfs(q2[2 + PR]);
    a1t[6] = bfs(q3[PR]); a1t[7] = bfs(q3[2 + PR]);
  }
  const f32x4 b1sv = ((const f32x4*)sb1l)[g];   // C-init: H bias rows 4g+j
  const f32x4 b1tv = ((const f32x4*)tb1l)[g];

  // ---- GEMM2 A (half-zeroed K=32, cat-hidden [Hs|Ht]) + bias select ----
  const f32x4* w2s4 = (const f32x4*)sW2l;
  const f32x4* w2t4 = (const f32x4*)tW2l;
  const f32x4* b2s4 = (const f32x4*)sb2l;
  const f32x4* b2t4 = (const f32x4*)tb2l;
  b16x8 a2s[2], a2t[2];
  f32x4 c2s[2], c2t[2];
#pragma unroll
  for (int to = 0; to < 2; ++to) {
    const int m = 8 * (c >> 2) + 4 * to + (c & 3);  // out-row c of tile `to` -> dim idx m
    const int d = 2 * m + PW;                       // actual latent dim (W2 row)
    f32x4 q = w2s4[d * 4 + g];                      // W2s[d][4g..4g+3]
    a2s[to] = (b16x8){bfs(q[0]), bfs(q[1]), bfs(q[2]), bfs(q[3]), 0, 0, 0, 0};
    q = w2t4[d * 4 + g];
    a2t[to] = (b16x8){0, 0, 0, 0, bfs(q[0]), bfs(q[1]), bfs(q[2]), bfs(q[3])};
    // C-init: b2[2*(8g+4to+j)+PW] = b2[16g+8to+2j+PW]
    f32x4 qa = b2s4[4 * g + 2 * to], qb = b2s4[4 * g + 2 * to + 1];
    c2s[to] = (f32x4){qa[PW], qa[2 + PW], qb[PW], qb[2 + PW]};
    qa = b2t4[4 * g + 2 * to]; qb = b2t4[4 * g + 2 * to + 1];
    c2t[to] = (f32x4){qa[PW], qa[2 + PW], qb[PW], qb[2 + PW]};
  }

#pragma unroll
  for (int T = 0; T < 2; ++T) {
    // B = read-parity z-state (already in B layout)
    const f32x4 z0 = zst[T][PR][0], z1 = zst[T][PR][1];
    b16x8 zB;
    zB[0] = bfs(z0[0]); zB[1] = bfs(z0[1]); zB[2] = bfs(z0[2]); zB[3] = bfs(z0[3]);
    zB[4] = bfs(z1[0]); zB[5] = bfs(z1[1]); zB[6] = bfs(z1[2]); zB[7] = bfs(z1[3]);
    const f32x4 hs = MFMA32(a1s, zB, b1sv);
    const f32x4 ht = MFMA32(a1t, zB, b1tv);
    // cat-hidden B operand: slots 0..3 = LeakyReLU(Hs rows 4g+j), 4..7 = Ht
    b16x8 hcat;
    hcat[0] = bfs(leaky(hs[0])); hcat[1] = bfs(leaky(hs[1]));
    hcat[2] = bfs(leaky(hs[2])); hcat[3] = bfs(leaky(hs[3]));
    hcat[4] = bfs(leaky(ht[0])); hcat[5] = bfs(leaky(ht[1]));
    hcat[6] = bfs(leaky(ht[2])); hcat[7] = bfs(leaky(ht[3]));
#pragma unroll
    for (int to = 0; to < 2; ++to) {
      const f32x4 ds = MFMA32(a2s[to], hcat, c2s[to]);
      const f32x4 dt = MFMA32(a2t[to], hcat, c2t[to]);
#pragma unroll
      for (int j = 0; j < 4; ++j) {
        const float sv = fminf(fmaxf(ds[j], -15.f), 15.f);
        const float e2 = __expf(2.f * sv);
        const float sc = __fdividef(e2 - 1.f, e2 + 1.f);   // tanh(sv)
        ldp[T] += sc;
        zst[T][PW][to][j] = zst[T][PW][to][j] * __expf(sc) + dt[j];
      }
    }
  }
}

__global__ __launch_bounds__(256) void realnvp_fwd(
    const float* __restrict__ x,
    const float* __restrict__ sW1, const float* __restrict__ sb1,
    const float* __restrict__ sW2, const float* __restrict__ sb2,
    const float* __restrict__ tW1, const float* __restrict__ tb1,
    const float* __restrict__ tW2, const float* __restrict__ tb2,
    float* __restrict__ out)
{
  const int lane = threadIdx.x & 63;
  const int wv = threadIdx.x >> 6;
  const int c = lane & 15, g = lane >> 4;
  const int rowbase = (blockIdx.x * 4 + wv) * 32;

  f32x4 zst[2][2][2];
  float ldp[2] = {0.f, 0.f};
#pragma unroll
  for (int T = 0; T < 2; ++T) {
    const f32x4* xr = (const f32x4*)(x + (size_t)(rowbase + T * 16 + c) * LAT);
    const f32x4 q0 = xr[4 * g], q1 = xr[4 * g + 1], q2 = xr[4 * g + 2], q3 = xr[4 * g + 3];
    zst[T][0][0] = (f32x4){q0[0], q0[2], q1[0], q1[2]};  // dims 16g+{0,2,4,6}
    zst[T][1][0] = (f32x4){q0[1], q0[3], q1[1], q1[3]};  // dims 16g+{1,3,5,7}
    zst[T][0][1] = (f32x4){q2[0], q2[2], q3[0], q3[2]};  // dims 16g+{8,10,12,14}
    zst[T][1][1] = (f32x4){q2[1], q2[3], q3[1], q3[3]};  // dims 16g+{9,11,13,15}
  }

#pragma unroll 1
  for (int lp = 0; lp < NL / 2; ++lp) {
    const int l0 = 2 * lp, l1 = 2 * lp + 1;
    layer_step<0>(sW1 + l0 * HID * LAT, sb1 + l0 * HID,
                  sW2 + l0 * LAT * HID, sb2 + l0 * LAT,
                  tW1 + l0 * HID * LAT, tb1 + l0 * HID,
                  tW2 + l0 * LAT * HID, tb2 + l0 * LAT,
                  zst, ldp, c, g);
    layer_step<1>(sW1 + l1 * HID * LAT, sb1 + l1 * HID,
                  sW2 + l1 * LAT * HID, sb2 + l1 * LAT,
                  tW1 + l1 * HID * LAT, tb1 + l1 * HID,
                  tW2 + l1 * LAT * HID, tb2 + l1 * LAT,
                  zst, ldp, c, g);
  }

#pragma unroll
  for (int T = 0; T < 2; ++T) {
    f32x4* zo = (f32x4*)(out + (size_t)(rowbase + T * 16 + c) * LAT);
    const f32x4 e0 = zst[T][0][0], o0 = zst[T][1][0];
    const f32x4 e1 = zst[T][0][1], o1 = zst[T][1][1];
    zo[4 * g]     = (f32x4){e0[0], o0[0], e0[1], o0[1]};
    zo[4 * g + 1] = (f32x4){e0[2], o0[2], e0[3], o0[3]};
    zo[4 * g + 2] = (f32x4){e1[0], o1[0], e1[1], o1[1]};
    zo[4 * g + 3] = (f32x4){e1[2], o1[2], e1[3], o1[3]};
  }
#pragma unroll
  for (int T = 0; T < 2; ++T) {
    ldp[T] += __shfl_xor(ldp[T], 16, 64);
    ldp[T] += __shfl_xor(ldp[T], 32, 64);
  }
  if (g < 2)
    out[(size_t)BATCHN * LAT + rowbase + g * 16 + c] = g ? ldp[1] : ldp[0];
}

extern "C" void kernel_launch(void* const* d_in, const int* in_sizes, int n_in,
                              void* d_out, int out_size, void* d_ws, size_t ws_size,
                              hipStream_t stream) {
  const float* x   = (const float*)d_in[0];
  const float* sW1 = (const float*)d_in[1];
  const float* sb1 = (const float*)d_in[2];
  const float* sW2 = (const float*)d_in[3];
  const float* sb2 = (const float*)d_in[4];
  const float* tW1 = (const float*)d_in[5];
  const float* tb1 = (const float*)d_in[6];
  const float* tW2 = (const float*)d_in[7];
  const float* tb2 = (const float*)d_in[8];
  float* out = (float*)d_out;
  dim3 grid(BATCHN / 128), block(256);
  hipLaunchKernelGGL(realnvp_fwd, grid, block, 0, stream,
                     x, sW1, sb1, sW2, sb2, tW1, tb1, tW2, tb2, out);
}

// Round 4
// 131.586 us; speedup vs baseline: 9.7899x; 1.7618x over previous
//
#include <hip/hip_runtime.h>
#include <hip/hip_bf16.h>

#define NL 16
#define HID 16
#define LAT 64
#define BATCHN 262144

typedef __attribute__((ext_vector_type(4))) float f32x4;
typedef __attribute__((ext_vector_type(8))) short b16x8;

// gfx950-verified MFMA (guide §3 / m89): lane 16g+c holds A[row=c][k=8g+j],
// B[k=8g+j][col=c]; D reg j = D[row=4g+j][col=c].
__device__ __forceinline__ f32x4 MFMA32(b16x8 a, b16x8 b, f32x4 c) {
  return __builtin_amdgcn_mfma_f32_16x16x32_bf16(a, b, c, 0, 0, 0);
}
__device__ __forceinline__ short bfs(float f) {
  union { __hip_bfloat16 h; short s; } u; u.h = __float2bfloat16(f); return u.s;
}
__device__ __forceinline__ float leaky(float v) { return fmaxf(v, 0.01f * v); }

// ---------------- setup: bake per-(layer,lane) fragments into d_ws ----------------
// dim map (parity PR = l&1): GEMM1 k=8g+u <-> latent dim 16g+2u+PR
// GEMM2 D tile to, row r=4g+j <-> dim 16g+8to+2j+PW
__global__ void prep_frags(
    const float* __restrict__ sW1, const float* __restrict__ sb1,
    const float* __restrict__ sW2, const float* __restrict__ sb2,
    const float* __restrict__ tW1, const float* __restrict__ tb1,
    const float* __restrict__ tW2, const float* __restrict__ tb2,
    b16x8* __restrict__ A1S, b16x8* __restrict__ A1T,
    b16x8* __restrict__ A2S, b16x8* __restrict__ A2T,
    f32x4* __restrict__ B1S, f32x4* __restrict__ B1T,
    f32x4* __restrict__ C2S, f32x4* __restrict__ C2T)
{
  const int l = blockIdx.x;       // layer
  const int lane = threadIdx.x;   // 0..63
  const int c = lane & 15, g = lane >> 4;
  const int PR = l & 1, PW = 1 - PR;
  const int idx = l * 64 + lane;

  b16x8 a;
  const float* w = sW1 + (l * HID + c) * LAT;
#pragma unroll
  for (int u = 0; u < 8; ++u) a[u] = bfs(w[16 * g + 2 * u + PR]);
  A1S[idx] = a;
  w = tW1 + (l * HID + c) * LAT;
#pragma unroll
  for (int u = 0; u < 8; ++u) a[u] = bfs(w[16 * g + 2 * u + PR]);
  A1T[idx] = a;
  B1S[idx] = ((const f32x4*)(sb1 + l * HID))[g];
  B1T[idx] = ((const f32x4*)(tb1 + l * HID))[g];

#pragma unroll
  for (int to = 0; to < 2; ++to) {
    const int m = 8 * (c >> 2) + 4 * to + (c & 3);
    const int d = 2 * m + PW;
    const int i2 = (l * 2 + to) * 64 + lane;
    b16x8 as = {0, 0, 0, 0, 0, 0, 0, 0}, at = {0, 0, 0, 0, 0, 0, 0, 0};
    const float* w2 = sW2 + (l * LAT + d) * HID + 4 * g;
#pragma unroll
    for (int j = 0; j < 4; ++j) as[j] = bfs(w2[j]);
    w2 = tW2 + (l * LAT + d) * HID + 4 * g;
#pragma unroll
    for (int j = 0; j < 4; ++j) at[4 + j] = bfs(w2[j]);
    A2S[i2] = as;
    A2T[i2] = at;
    f32x4 cs, ct;
#pragma unroll
    for (int j = 0; j < 4; ++j) {
      cs[j] = sb2[l * LAT + 16 * g + 8 * to + 2 * j + PW];
      ct[j] = tb2[l * LAT + 16 * g + 8 * to + 2 * j + PW];
    }
    C2S[i2] = cs;
    C2T[i2] = ct;
  }
}

// ---------------- main: one coupling layer ----------------
// zst[T][p][uh][j] = z[row=rowbase+16T+c][dim = 16g + 2*(4uh+j) + p]  (f32)
// zbf[T][p] = same 8 values in bf16 = B-operand of GEMM1 (k=8g+u).
template<int PR>
__device__ __forceinline__ void layer_step(
    b16x8 a1s, b16x8 a1t, b16x8 a2s0, b16x8 a2s1, b16x8 a2t0, b16x8 a2t1,
    f32x4 b1sv, f32x4 b1tv, f32x4 c2s0, f32x4 c2s1, f32x4 c2t0, f32x4 c2t1,
    f32x4 (&zst)[2][2][2], b16x8 (&zbf)[2][2], float (&ldp)[2])
{
  constexpr int PW = 1 - PR;
#pragma unroll
  for (int T = 0; T < 2; ++T) {
    const f32x4 hs = MFMA32(a1s, zbf[T][PR], b1sv);
    const f32x4 ht = MFMA32(a1t, zbf[T][PR], b1tv);
    b16x8 hcat;   // slots 0-3: LeakyReLU(Hs rows 4g+j); 4-7: Ht
    hcat[0] = bfs(leaky(hs[0])); hcat[1] = bfs(leaky(hs[1]));
    hcat[2] = bfs(leaky(hs[2])); hcat[3] = bfs(leaky(hs[3]));
    hcat[4] = bfs(leaky(ht[0])); hcat[5] = bfs(leaky(ht[1]));
    hcat[6] = bfs(leaky(ht[2])); hcat[7] = bfs(leaky(ht[3]));
    const f32x4 ds0 = MFMA32(a2s0, hcat, c2s0);
    const f32x4 dt0 = MFMA32(a2t0, hcat, c2t0);
    const f32x4 ds1 = MFMA32(a2s1, hcat, c2s1);
    const f32x4 dt1 = MFMA32(a2t1, hcat, c2t1);
    b16x8 nz;
#pragma unroll
    for (int to = 0; to < 2; ++to) {
      const f32x4 ds = to ? ds1 : ds0;
      const f32x4 dt = to ? dt1 : dt0;
#pragma unroll
      for (int j = 0; j < 4; ++j) {
        const float sv = fminf(fmaxf(ds[j], -15.f), 15.f);
        const float e2 = __expf(2.f * sv);
        const float sc = __fdividef(e2 - 1.f, e2 + 1.f);   // tanh
        ldp[T] += sc;
        const float z = zst[T][PW][to][j] * __expf(sc) + dt[j];
        zst[T][PW][to][j] = z;
        nz[4 * to + j] = bfs(z);
      }
    }
    zbf[T][PW] = nz;
  }
}

__global__ __launch_bounds__(256) void realnvp_fwd(
    const float* __restrict__ x, float* __restrict__ out,
    const b16x8* __restrict__ A1S, const b16x8* __restrict__ A1T,
    const b16x8* __restrict__ A2S, const b16x8* __restrict__ A2T,
    const f32x4* __restrict__ B1S, const f32x4* __restrict__ B1T,
    const f32x4* __restrict__ C2S, const f32x4* __restrict__ C2T)
{
  const int lane = threadIdx.x & 63;
  const int wv = threadIdx.x >> 6;
  const int c = lane & 15, g = lane >> 4;
  const int rowbase = (blockIdx.x * 4 + wv) * 32;

  f32x4 zst[2][2][2];
  b16x8 zbf[2][2];
  float ldp[2] = {0.f, 0.f};
#pragma unroll
  for (int T = 0; T < 2; ++T) {
    const f32x4* xr = (const f32x4*)(x + (size_t)(rowbase + T * 16 + c) * LAT);
    const f32x4 q0 = xr[4 * g], q1 = xr[4 * g + 1], q2 = xr[4 * g + 2], q3 = xr[4 * g + 3];
    zst[T][0][0] = (f32x4){q0[0], q0[2], q1[0], q1[2]};
    zst[T][1][0] = (f32x4){q0[1], q0[3], q1[1], q1[3]};
    zst[T][0][1] = (f32x4){q2[0], q2[2], q3[0], q3[2]};
    zst[T][1][1] = (f32x4){q2[1], q2[3], q3[1], q3[3]};
#pragma unroll
    for (int p = 0; p < 2; ++p) {
      b16x8 zb;
#pragma unroll
      for (int j = 0; j < 4; ++j) {
        zb[j] = bfs(zst[T][p][0][j]);
        zb[4 + j] = bfs(zst[T][p][1][j]);
      }
      zbf[T][p] = zb;
    }
  }

#pragma unroll 1
  for (int lp = 0; lp < NL / 2; ++lp) {
    {
      const int i1 = (2 * lp) * 64 + lane, i2 = (4 * lp) * 64 + lane;
      layer_step<0>(A1S[i1], A1T[i1], A2S[i2], A2S[i2 + 64], A2T[i2], A2T[i2 + 64],
                    B1S[i1], B1T[i1], C2S[i2], C2S[i2 + 64], C2T[i2], C2T[i2 + 64],
                    zst, zbf, ldp);
    }
    {
      const int i1 = (2 * lp + 1) * 64 + lane, i2 = (4 * lp + 2) * 64 + lane;
      layer_step<1>(A1S[i1], A1T[i1], A2S[i2], A2S[i2 + 64], A2T[i2], A2T[i2 + 64],
                    B1S[i1], B1T[i1], C2S[i2], C2S[i2 + 64], C2T[i2], C2T[i2 + 64],
                    zst, zbf, ldp);
    }
  }

#pragma unroll
  for (int T = 0; T < 2; ++T) {
    f32x4* zo = (f32x4*)(out + (size_t)(rowbase + T * 16 + c) * LAT);
    const f32x4 e0 = zst[T][0][0], o0 = zst[T][1][0];
    const f32x4 e1 = zst[T][0][1], o1 = zst[T][1][1];
    zo[4 * g]     = (f32x4){e0[0], o0[0], e0[1], o0[1]};
    zo[4 * g + 1] = (f32x4){e0[2], o0[2], e0[3], o0[3]};
    zo[4 * g + 2] = (f32x4){e1[0], o1[0], e1[1], o1[1]};
    zo[4 * g + 3] = (f32x4){e1[2], o1[2], e1[3], o1[3]};
  }
#pragma unroll
  for (int T = 0; T < 2; ++T) {
    ldp[T] += __shfl_xor(ldp[T], 16, 64);
    ldp[T] += __shfl_xor(ldp[T], 32, 64);
  }
  if (g < 2)
    out[(size_t)BATCHN * LAT + rowbase + g * 16 + c] = g ? ldp[1] : ldp[0];
}

extern "C" void kernel_launch(void* const* d_in, const int* in_sizes, int n_in,
                              void* d_out, int out_size, void* d_ws, size_t ws_size,
                              hipStream_t stream) {
  const float* x   = (const float*)d_in[0];
  const float* sW1 = (const float*)d_in[1];
  const float* sb1 = (const float*)d_in[2];
  const float* sW2 = (const float*)d_in[3];
  const float* sb2 = (const float*)d_in[4];
  const float* tW1 = (const float*)d_in[5];
  const float* tb1 = (const float*)d_in[6];
  const float* tW2 = (const float*)d_in[7];
  const float* tb2 = (const float*)d_in[8];
  float* out = (float*)d_out;

  char* w = (char*)d_ws;
  b16x8* A1S = (b16x8*)w;            w += NL * 64 * sizeof(b16x8);
  b16x8* A1T = (b16x8*)w;            w += NL * 64 * sizeof(b16x8);
  b16x8* A2S = (b16x8*)w;            w += NL * 128 * sizeof(b16x8);
  b16x8* A2T = (b16x8*)w;            w += NL * 128 * sizeof(b16x8);
  f32x4* B1S = (f32x4*)w;            w += NL * 64 * sizeof(f32x4);
  f32x4* B1T = (f32x4*)w;            w += NL * 64 * sizeof(f32x4);
  f32x4* C2S = (f32x4*)w;            w += NL * 128 * sizeof(f32x4);
  f32x4* C2T = (f32x4*)w;            w += NL * 128 * sizeof(f32x4);

  hipLaunchKernelGGL(prep_frags, dim3(NL), dim3(64), 0, stream,
                     sW1, sb1, sW2, sb2, tW1, tb1, tW2, tb2,
                     A1S, A1T, A2S, A2T, B1S, B1T, C2S, C2T);
  hipLaunchKernelGGL(realnvp_fwd, dim3(BATCHN / 128), dim3(256), 0, stream,
                     x, out, A1S, A1T, A2S, A2T, B1S, B1T, C2S, C2T);
}

// Round 6
// 112.395 us; speedup vs baseline: 11.4614x; 1.1707x over previous
//
#include <hip/hip_runtime.h>
#include <hip/hip_bf16.h>

#define NL 16
#define HID 16
#define LAT 64
#define BATCHN 262144

typedef __attribute__((ext_vector_type(4))) float f32x4;
typedef __attribute__((ext_vector_type(8))) short b16x8;

// gfx950-verified MFMA (guide §3 / m89): lane 16g+c holds A[row=c][k=8g+j],
// B[k=8g+j][col=c]; D reg j = D[row=4g+j][col=c].
__device__ __forceinline__ f32x4 MFMA32(b16x8 a, b16x8 b, f32x4 c) {
  return __builtin_amdgcn_mfma_f32_16x16x32_bf16(a, b, c, 0, 0, 0);
}

// pure-C RNE bf16 pair-pack (no NaN check -- inputs provably finite).
// Bit-exact with __float2bfloat16 RNE for finite values.
__device__ __forceinline__ unsigned pk2(float lo, float hi) {
  unsigned a = __float_as_uint(lo), b = __float_as_uint(hi);
  a = (a + 0x7fffu + ((a >> 16) & 1u)) >> 16;
  b = (b + 0x7fffu + ((b >> 16) & 1u)) & 0xffff0000u;
  return b | a;
}

#if __has_builtin(__builtin_amdgcn_exp2f)
__device__ __forceinline__ float fexp2(float x) { return __builtin_amdgcn_exp2f(x); }
#else
__device__ __forceinline__ float fexp2(float x) { return __expf(0.6931471805599453f * x); }
#endif
#if __has_builtin(__builtin_amdgcn_rcpf)
__device__ __forceinline__ float frcp(float x) { return __builtin_amdgcn_rcpf(x); }
#else
__device__ __forceinline__ float frcp(float x) { return __fdividef(1.f, x); }
#endif

__device__ __forceinline__ short bfs(float f) {
  union { __hip_bfloat16 h; short s; } u; u.h = __float2bfloat16(f); return u.s;
}
__device__ __forceinline__ float leaky(float v) { return fmaxf(v, 0.01f * v); }
#define TWO_LOG2E 2.885390081777927f   /* 2/ln2 */
#define LOG2E     1.442695040888963f

// ---------------- setup: bake per-(layer,lane) fragments into d_ws ----------------
__global__ void prep_frags(
    const float* __restrict__ sW1, const float* __restrict__ sb1,
    const float* __restrict__ sW2, const float* __restrict__ sb2,
    const float* __restrict__ tW1, const float* __restrict__ tb1,
    const float* __restrict__ tW2, const float* __restrict__ tb2,
    b16x8* __restrict__ A1S, b16x8* __restrict__ A1T,
    b16x8* __restrict__ A2S, b16x8* __restrict__ A2T,
    f32x4* __restrict__ B1S, f32x4* __restrict__ B1T,
    f32x4* __restrict__ C2S, f32x4* __restrict__ C2T)
{
  const int l = blockIdx.x;
  const int lane = threadIdx.x;
  const int c = lane & 15, g = lane >> 4;
  const int PR = l & 1, PW = 1 - PR;
  const int idx = l * 64 + lane;

  b16x8 a;
  const float* w = sW1 + (l * HID + c) * LAT;
#pragma unroll
  for (int u = 0; u < 8; ++u) a[u] = bfs(w[16 * g + 2 * u + PR]);
  A1S[idx] = a;
  w = tW1 + (l * HID + c) * LAT;
#pragma unroll
  for (int u = 0; u < 8; ++u) a[u] = bfs(w[16 * g + 2 * u + PR]);
  A1T[idx] = a;
  B1S[idx] = ((const f32x4*)(sb1 + l * HID))[g];
  B1T[idx] = ((const f32x4*)(tb1 + l * HID))[g];

#pragma unroll
  for (int to = 0; to < 2; ++to) {
    const int m = 8 * (c >> 2) + 4 * to + (c & 3);
    const int d = 2 * m + PW;
    const int i2 = (l * 2 + to) * 64 + lane;
    b16x8 as = {0, 0, 0, 0, 0, 0, 0, 0}, at = {0, 0, 0, 0, 0, 0, 0, 0};
    const float* w2 = sW2 + (l * LAT + d) * HID + 4 * g;
#pragma unroll
    for (int j = 0; j < 4; ++j) as[j] = bfs(w2[j]);
    w2 = tW2 + (l * LAT + d) * HID + 4 * g;
#pragma unroll
    for (int j = 0; j < 4; ++j) at[4 + j] = bfs(w2[j]);
    A2S[i2] = as;
    A2T[i2] = at;
    f32x4 cs, ct;
#pragma unroll
    for (int j = 0; j < 4; ++j) {
      cs[j] = sb2[l * LAT + 16 * g + 8 * to + 2 * j + PW];
      ct[j] = tb2[l * LAT + 16 * g + 8 * to + 2 * j + PW];
    }
    C2S[i2] = cs;
    C2T[i2] = ct;
  }
}

// ---------------- main: one coupling layer ----------------
// zst[T][p][uh][j] = z[row=rowbase+16T+c][dim = 16g + 2*(4uh+j) + p]  (f32)
// zbf[T][p] = same 8 values bf16-packed = B-operand of GEMM1 (k=8g+u).
template<int PR>
__device__ __forceinline__ void layer_step(
    b16x8 a1s, b16x8 a1t, b16x8 a2s0, b16x8 a2s1, b16x8 a2t0, b16x8 a2t1,
    f32x4 b1sv, f32x4 b1tv, f32x4 c2s0, f32x4 c2s1, f32x4 c2t0, f32x4 c2t1,
    f32x4 (&zst)[2][2][2], b16x8 (&zbf)[2][2], float (&ldp)[2])
{
  constexpr int PW = 1 - PR;
#pragma unroll
  for (int T = 0; T < 2; ++T) {
    const f32x4 hs = MFMA32(a1s, zbf[T][PR], b1sv);
    const f32x4 ht = MFMA32(a1t, zbf[T][PR], b1tv);
    union { unsigned u[4]; b16x8 v; } hc;   // [LeakyReLU(Hs) | LeakyReLU(Ht)]
    hc.u[0] = pk2(leaky(hs[0]), leaky(hs[1]));
    hc.u[1] = pk2(leaky(hs[2]), leaky(hs[3]));
    hc.u[2] = pk2(leaky(ht[0]), leaky(ht[1]));
    hc.u[3] = pk2(leaky(ht[2]), leaky(ht[3]));
    const f32x4 ds0 = MFMA32(a2s0, hc.v, c2s0);
    const f32x4 dt0 = MFMA32(a2t0, hc.v, c2t0);
    const f32x4 ds1 = MFMA32(a2s1, hc.v, c2s1);
    const f32x4 dt1 = MFMA32(a2t1, hc.v, c2t1);
    f32x4 z0 = zst[T][PW][0], z1 = zst[T][PW][1];
#pragma unroll
    for (int j = 0; j < 4; ++j) {
      // tanh(s) = 1 - 2/(exp2(s*2/ln2)+1); exp2 saturation gives exact +-1 limits
      const float w0 = fexp2(TWO_LOG2E * ds0[j]);
      const float s0 = fmaf(-2.f, frcp(w0 + 1.f), 1.f);
      ldp[T] += s0;
      z0[j] = fmaf(z0[j], fexp2(LOG2E * s0), dt0[j]);
      const float w1 = fexp2(TWO_LOG2E * ds1[j]);
      const float s1 = fmaf(-2.f, frcp(w1 + 1.f), 1.f);
      ldp[T] += s1;
      z1[j] = fmaf(z1[j], fexp2(LOG2E * s1), dt1[j]);
    }
    zst[T][PW][0] = z0;
    zst[T][PW][1] = z1;
    union { unsigned u[4]; b16x8 v; } nz;
    nz.u[0] = pk2(z0[0], z0[1]);
    nz.u[1] = pk2(z0[2], z0[3]);
    nz.u[2] = pk2(z1[0], z1[1]);
    nz.u[3] = pk2(z1[2], z1[3]);
    zbf[T][PW] = nz.v;
  }
}

__global__ __launch_bounds__(256) void realnvp_fwd(
    const float* __restrict__ x, float* __restrict__ out,
    const b16x8* __restrict__ A1S, const b16x8* __restrict__ A1T,
    const b16x8* __restrict__ A2S, const b16x8* __restrict__ A2T,
    const f32x4* __restrict__ B1S, const f32x4* __restrict__ B1T,
    const f32x4* __restrict__ C2S, const f32x4* __restrict__ C2T)
{
  const int lane = threadIdx.x & 63;
  const int wv = threadIdx.x >> 6;
  const int c = lane & 15, g = lane >> 4;
  const int rowbase = (blockIdx.x * 4 + wv) * 32;

  f32x4 zst[2][2][2];
  b16x8 zbf[2][2];
  float ldp[2] = {0.f, 0.f};
#pragma unroll
  for (int T = 0; T < 2; ++T) {
    const f32x4* xr = (const f32x4*)(x + (size_t)(rowbase + T * 16 + c) * LAT);
    const f32x4 q0 = xr[4 * g], q1 = xr[4 * g + 1], q2 = xr[4 * g + 2], q3 = xr[4 * g + 3];
    zst[T][0][0] = (f32x4){q0[0], q0[2], q1[0], q1[2]};
    zst[T][1][0] = (f32x4){q0[1], q0[3], q1[1], q1[3]};
    zst[T][0][1] = (f32x4){q2[0], q2[2], q3[0], q3[2]};
    zst[T][1][1] = (f32x4){q2[1], q2[3], q3[1], q3[3]};
#pragma unroll
    for (int p = 0; p < 2; ++p) {
      union { unsigned u[4]; b16x8 v; } zb;
      zb.u[0] = pk2(zst[T][p][0][0], zst[T][p][0][1]);
      zb.u[1] = pk2(zst[T][p][0][2], zst[T][p][0][3]);
      zb.u[2] = pk2(zst[T][p][1][0], zst[T][p][1][1]);
      zb.u[3] = pk2(zst[T][p][1][2], zst[T][p][1][3]);
      zbf[T][p] = zb.v;
    }
  }

#pragma unroll 1
  for (int lp = 0; lp < NL / 2; ++lp) {
    {
      const int i1 = (2 * lp) * 64 + lane, i2 = (4 * lp) * 64 + lane;
      layer_step<0>(A1S[i1], A1T[i1], A2S[i2], A2S[i2 + 64], A2T[i2], A2T[i2 + 64],
                    B1S[i1], B1T[i1], C2S[i2], C2S[i2 + 64], C2T[i2], C2T[i2 + 64],
                    zst, zbf, ldp);
    }
    {
      const int i1 = (2 * lp + 1) * 64 + lane, i2 = (4 * lp + 2) * 64 + lane;
      layer_step<1>(A1S[i1], A1T[i1], A2S[i2], A2S[i2 + 64], A2T[i2], A2T[i2 + 64],
                    B1S[i1], B1T[i1], C2S[i2], C2S[i2 + 64], C2T[i2], C2T[i2 + 64],
                    zst, zbf, ldp);
    }
  }

#pragma unroll
  for (int T = 0; T < 2; ++T) {
    f32x4* zo = (f32x4*)(out + (size_t)(rowbase + T * 16 + c) * LAT);
    const f32x4 e0 = zst[T][0][0], o0 = zst[T][1][0];
    const f32x4 e1 = zst[T][0][1], o1 = zst[T][1][1];
    zo[4 * g]     = (f32x4){e0[0], o0[0], e0[1], o0[1]};
    zo[4 * g + 1] = (f32x4){e0[2], o0[2], e0[3], o0[3]};
    zo[4 * g + 2] = (f32x4){e1[0], o1[0], e1[1], o1[1]};
    zo[4 * g + 3] = (f32x4){e1[2], o1[2], e1[3], o1[3]};
  }
#pragma unroll
  for (int T = 0; T < 2; ++T) {
    ldp[T] += __shfl_xor(ldp[T], 16, 64);
    ldp[T] += __shfl_xor(ldp[T], 32, 64);
  }
  if (g < 2)
    out[(size_t)BATCHN * LAT + rowbase + g * 16 + c] = g ? ldp[1] : ldp[0];
}

extern "C" void kernel_launch(void* const* d_in, const int* in_sizes, int n_in,
                              void* d_out, int out_size, void* d_ws, size_t ws_size,
                              hipStream_t stream) {
  const float* x   = (const float*)d_in[0];
  const float* sW1 = (const float*)d_in[1];
  const float* sb1 = (const float*)d_in[2];
  const float* sW2 = (const float*)d_in[3];
  const float* sb2 = (const float*)d_in[4];
  const float* tW1 = (const float*)d_in[5];
  const float* tb1 = (const float*)d_in[6];
  const float* tW2 = (const float*)d_in[7];
  const float* tb2 = (const float*)d_in[8];
  float* out = (float*)d_out;

  char* w = (char*)d_ws;
  b16x8* A1S = (b16x8*)w;            w += NL * 64 * sizeof(b16x8);
  b16x8* A1T = (b16x8*)w;            w += NL * 64 * sizeof(b16x8);
  b16x8* A2S = (b16x8*)w;            w += NL * 128 * sizeof(b16x8);
  b16x8* A2T = (b16x8*)w;            w += NL * 128 * sizeof(b16x8);
  f32x4* B1S = (f32x4*)w;            w += NL * 64 * sizeof(f32x4);
  f32x4* B1T = (f32x4*)w;            w += NL * 64 * sizeof(f32x4);
  f32x4* C2S = (f32x4*)w;            w += NL * 128 * sizeof(f32x4);
  f32x4* C2T = (f32x4*)w;            w += NL * 128 * sizeof(f32x4);

  hipLaunchKernelGGL(prep_frags, dim3(NL), dim3(64), 0, stream,
                     sW1, sb1, sW2, sb2, tW1, tb1, tW2, tb2,
                     A1S, A1T, A2S, A2T, B1S, B1T, C2S, C2T);
  hipLaunchKernelGGL(realnvp_fwd, dim3(BATCHN / 128), dim3(256), 0, stream,
                     x, out, A1S, A1T, A2S, A2T, B1S, B1T, C2S, C2T);
}